// Round 16
// baseline (380.681 us; speedup 1.0000x reference)
//
#include <hip/hip_runtime.h>

#define DIM 512
#define BATCH 65536
#define BM 32
#define THREADS 512
#define TILES 4
#define NBLK (BATCH / (BM * TILES))   // 512 blocks

typedef float f32x4 __attribute__((ext_vector_type(4)));
typedef float f32x16 __attribute__((ext_vector_type(16)));
typedef __bf16 bf16x8 __attribute__((ext_vector_type(8)));

__device__ __forceinline__ unsigned f2bf(float f) {
    unsigned u = __float_as_uint(f);
    return (u + 0x7FFFu + ((u >> 16) & 1u)) >> 16;
}

// Sf in MFMA-B-fragment order: Sf[((k0*16 + np)*64 + lane)*8 + j]
//   = bf16( A[n][k] + A[k][n] ),  n = np*32 + (lane&31),  k = k0*16 + (lane>>5)*8 + j
__global__ void prep_Sfrag(const float* __restrict__ A, unsigned short* __restrict__ Sf) {
    int idx = blockIdx.x * 256 + threadIdx.x;    // 0..32767 : (k0, np, lane)
    int lane = idx & 63;
    int np   = (idx >> 6) & 15;
    int k0   = idx >> 10;
    int n     = np * 32 + (lane & 31);
    int kbase = k0 * 16 + (lane >> 5) * 8;
    unsigned short tmp[8];
    #pragma unroll
    for (int j = 0; j < 8; ++j) {
        int k = kbase + j;
        tmp[j] = (unsigned short)f2bf(A[n * DIM + k] + A[k * DIM + n]);
    }
    *(uint4*)(Sf + (size_t)idx * 8) = *(const uint4*)tmp;
}

// out[b][0:512] = p[b] + q[b].S ; out[b][512:1024] = q[b]
// A-direct variant: NO q LDS staging. The A fragment is loaded straight from
// global q (2 x f32x4 per k-iter, L1/L2-resident; the passthrough copy's
// cached loads pre-warm L2) and converted to bf16 in-register (v_cvt_pk).
// k-loop is barrier-free; only the sc epilogue synchronizes. LDS = 32 KB.
__global__ __launch_bounds__(THREADS, 4)
void gemm_kernel(const float* __restrict__ pq,
                 const unsigned short* __restrict__ Sf,
                 float* __restrict__ out) {
    __shared__ float sc[BM * 256];                 // 32 KB epilogue scratch
    const int tid  = threadIdx.x;
    const int wid  = tid >> 6;
    const int lane = tid & 63;
    const int row  = lane & 31;
    const int khalf = lane >> 5;
    const int rb = blockIdx.x * (BM * TILES);
    const unsigned short* Sfp = Sf + ((size_t)(wid * 2) * 64 + lane) * 8;

    const int r0 = tid >> 5, c8 = tid & 31;        // copy slots: rows r0, r0+16
    const int r1 = r0 + 16;

    f32x4 stg[4];   // passthrough q, issued before a khalf, stored right after

    auto issue_q = [&](int t, int half) {          // CACHED loads: warm L2 for A
        size_t g0 = (size_t)(rb + t * BM + r0) * 1024 + 512 + half * 256 + c8 * 8;
        size_t g1 = (size_t)(rb + t * BM + r1) * 1024 + 512 + half * 256 + c8 * 8;
        stg[0] = *(const f32x4*)(pq + g0);
        stg[1] = *(const f32x4*)(pq + g0 + 4);
        stg[2] = *(const f32x4*)(pq + g1);
        stg[3] = *(const f32x4*)(pq + g1 + 4);
    };
    auto store_q = [&](int t, int half) {
        size_t g0 = (size_t)(rb + t * BM + r0) * 1024 + 512 + half * 256 + c8 * 8;
        size_t g1 = (size_t)(rb + t * BM + r1) * 1024 + 512 + half * 256 + c8 * 8;
        __builtin_nontemporal_store(stg[0], (f32x4*)(out + g0));
        __builtin_nontemporal_store(stg[1], (f32x4*)(out + g0 + 4));
        __builtin_nontemporal_store(stg[2], (f32x4*)(out + g1));
        __builtin_nontemporal_store(stg[3], (f32x4*)(out + g1 + 4));
    };
    auto khalf_direct = [&](int t, int half, f32x16& acc0, f32x16& acc1) {
        const unsigned short* sp = Sfp + (size_t)(half * 16) * 8192;
        const float* qp = pq + (size_t)(rb + t * BM + row) * 1024 + 512
                             + half * 256 + khalf * 8;
        f32x4 alo_c = *(const f32x4*)(qp);
        f32x4 ahi_c = *(const f32x4*)(qp + 4);
        bf16x8 b0_c = *(const bf16x8*)(sp);
        bf16x8 b1_c = *(const bf16x8*)(sp + 512);
        #pragma unroll
        for (int k = 0; k < 16; ++k) {
            f32x4 alo_n, ahi_n; bf16x8 b0_n, b1_n;
            if (k < 15) {
                alo_n = *(const f32x4*)(qp + (k + 1) * 16);
                ahi_n = *(const f32x4*)(qp + (k + 1) * 16 + 4);
                b0_n  = *(const bf16x8*)(sp + (size_t)(k + 1) * 8192);
                b1_n  = *(const bf16x8*)(sp + (size_t)(k + 1) * 8192 + 512);
            }
            bf16x8 a;
            a[0] = (__bf16)alo_c[0]; a[1] = (__bf16)alo_c[1];
            a[2] = (__bf16)alo_c[2]; a[3] = (__bf16)alo_c[3];
            a[4] = (__bf16)ahi_c[0]; a[5] = (__bf16)ahi_c[1];
            a[6] = (__bf16)ahi_c[2]; a[7] = (__bf16)ahi_c[3];
            acc0 = __builtin_amdgcn_mfma_f32_32x32x16_bf16(a, b0_c, acc0, 0, 0, 0);
            acc1 = __builtin_amdgcn_mfma_f32_32x32x16_bf16(a, b1_c, acc1, 0, 0, 0);
            if (k < 15) { alo_c = alo_n; ahi_c = ahi_n; b0_c = b0_n; b1_c = b1_n; }
        }
    };
    auto epilogue = [&](int tile, const f32x16& acc0, const f32x16& acc1) {
        int tb = rb + tile * BM;
        #pragma unroll
        for (int pass = 0; pass < 2; ++pass) {
            const f32x16& ac = pass ? acc1 : acc0;
            #pragma unroll
            for (int reg = 0; reg < 16; ++reg) {
                int r = (reg & 3) + 8 * (reg >> 2) + 4 * khalf;
                sc[r * 256 + wid * 32 + row] = ac[reg];   // 2-way bank alias: free
            }
            __syncthreads();
            #pragma unroll
            for (int j = 0; j < 4; ++j) {
                int c = tid + j * 512;
                int r = c >> 6, cc = c & 63;
                int gcol = (cc >> 3) * 64 + (cc & 7) * 4 + pass * 32;
                size_t g = (size_t)(tb + r) * 1024 + gcol;
                f32x4 v  = *(const f32x4*)(sc + r * 256 + cc * 4);
                f32x4 pv = __builtin_nontemporal_load((const f32x4*)(pq + g));
                __builtin_nontemporal_store(pv + v, (f32x4*)(out + g));
            }
            __syncthreads();
        }
    };

    f32x16 acc0, acc1;
    for (int t = 0; t < TILES; ++t) {
        acc0 = f32x16{};
        acc1 = f32x16{};
        issue_q(t, 0);                      // warms L2 for khalf 0's A reads
        khalf_direct(t, 0, acc0, acc1);
        store_q(t, 0);
        issue_q(t, 1);                      // warms L2 for khalf 1's A reads
        khalf_direct(t, 1, acc0, acc1);
        store_q(t, 1);
        epilogue(t, acc0, acc1);
    }
}

extern "C" void kernel_launch(void* const* d_in, const int* in_sizes, int n_in,
                              void* d_out, int out_size, void* d_ws, size_t ws_size,
                              hipStream_t stream) {
    const float* pq = (const float*)d_in[0];
    const float* A  = (const float*)d_in[1];
    float* out = (float*)d_out;
    unsigned short* Sf = (unsigned short*)d_ws;   // 512 KB fragment-ordered S

    prep_Sfrag<<<128, 256, 0, stream>>>(A, Sf);
    gemm_kernel<<<NBLK, THREADS, 0, stream>>>(pq, Sf, out);
}

// Round 17
// 138.525 us; speedup vs baseline: 2.7481x; 2.7481x over previous
//
#include <hip/hip_runtime.h>

#define DIM 512
#define BATCH 65536
#define BM 32
#define THREADS 512
#define TILES 4
#define NBLK (BATCH / (BM * TILES))   // 512 blocks

typedef float f32x4 __attribute__((ext_vector_type(4)));
typedef float f32x16 __attribute__((ext_vector_type(16)));
typedef __bf16 bf16x8 __attribute__((ext_vector_type(8)));

__device__ __forceinline__ unsigned f2bf(float f) {
    unsigned u = __float_as_uint(f);
    return (u + 0x7FFFu + ((u >> 16) & 1u)) >> 16;
}

// Sf in MFMA-B-fragment order: Sf[((k0*16 + np)*64 + lane)*8 + j]
//   = bf16( A[n][k] + A[k][n] ),  n = np*32 + (lane&31),  k = k0*16 + (lane>>5)*8 + j
// Grid 512x64: one wave per block, 2 blocks/CU (was 128x256 = half the CUs idle).
__global__ void prep_Sfrag(const float* __restrict__ A, unsigned short* __restrict__ Sf) {
    int idx = blockIdx.x * 64 + threadIdx.x;     // 0..32767 : (k0, np, lane)
    int lane = idx & 63;
    int np   = (idx >> 6) & 15;
    int k0   = idx >> 10;
    int n     = np * 32 + (lane & 31);
    int kbase = k0 * 16 + (lane >> 5) * 8;
    unsigned short tmp[8];
    #pragma unroll
    for (int j = 0; j < 8; ++j) {
        int k = kbase + j;
        tmp[j] = (unsigned short)f2bf(A[n * DIM + k] + A[k * DIM + n]);
    }
    *(uint4*)(Sf + (size_t)idx * 8) = *(const uint4*)tmp;
}

// out[b][0:512] = p[b] + q[b].S ; out[b][512:1024] = q[b]
// R9 phase-pipelined structure + (1) 16-slot XOR swizzle (8-slot was a 4-way
// ds_read_b128 bank conflict, 2.1M counted), (2) distance-2 B prefetch via
// step-2 unroll in the same named-register rotation idiom R9 proved SROA-safe.
__global__ __launch_bounds__(THREADS, 4)
void gemm_kernel(const float* __restrict__ pq,
                 const unsigned short* __restrict__ Sf,
                 float* __restrict__ out) {
    __shared__ __align__(16) unsigned short qh[2][BM * 256];  // 2 x 16 KB bf16 half-K
    __shared__ float sc[BM * 256];                            // 32 KB epilogue scratch
    const int tid  = threadIdx.x;
    const int wid  = tid >> 6;
    const int lane = tid & 63;
    const int row  = lane & 31;
    const int khalf = lane >> 5;
    const int rb = blockIdx.x * (BM * TILES);
    const unsigned short* Sfp = Sf + ((size_t)(wid * 2) * 64 + lane) * 8;

    f32x4 stg[4];   // staged q for the next phase (consumed within one phase)

    auto issue_loads = [&](int ph) {
        int tile = ph >> 1, half = ph & 1;
        #pragma unroll
        for (int i = 0; i < 2; ++i) {
            int slot = i * THREADS + tid;
            int r = slot >> 5, c8 = slot & 31;
            size_t g = (size_t)(rb + tile * BM + r) * 1024 + 512 + half * 256 + c8 * 8;
            stg[2*i]   = __builtin_nontemporal_load((const f32x4*)(pq + g));
            stg[2*i+1] = __builtin_nontemporal_load((const f32x4*)(pq + g + 4));
        }
    };
    auto write_back = [&](int ph) {
        int tile = ph >> 1, half = ph & 1;
        unsigned short* dst = qh[ph & 1];
        #pragma unroll
        for (int i = 0; i < 2; ++i) {
            int slot = i * THREADS + tid;
            int r = slot >> 5, c8 = slot & 31;
            size_t g = (size_t)(rb + tile * BM + r) * 1024 + 512 + half * 256 + c8 * 8;
            __builtin_nontemporal_store(stg[2*i],   (f32x4*)(out + g));     // q passthrough
            __builtin_nontemporal_store(stg[2*i+1], (f32x4*)(out + g + 4));
            unsigned u0 = f2bf(stg[2*i].x)   | (f2bf(stg[2*i].y)   << 16);
            unsigned u1 = f2bf(stg[2*i].z)   | (f2bf(stg[2*i].w)   << 16);
            unsigned u2 = f2bf(stg[2*i+1].x) | (f2bf(stg[2*i+1].y) << 16);
            unsigned u3 = f2bf(stg[2*i+1].z) | (f2bf(stg[2*i+1].w) << 16);
            int b = r * 512 + ((c8 * 16) ^ ((r & 15) << 4));   // 16-slot swizzle
            *(uint4*)((char*)dst + b) = make_uint4(u0, u1, u2, u3);
        }
    };
    auto khalf_loop = [&](int ph, f32x16& acc0, f32x16& acc1) {
        int half = ph & 1;
        const unsigned short* buf = qh[ph & 1];
        const unsigned short* sp = Sfp + (size_t)(half * 16) * 8192;
        // distance-2 prefetch, step-2 unroll: c = k, d = k+1 in flight
        bf16x8 b0_c = *(const bf16x8*)(sp);
        bf16x8 b1_c = *(const bf16x8*)(sp + 512);
        bf16x8 b0_d = *(const bf16x8*)(sp + 8192);
        bf16x8 b1_d = *(const bf16x8*)(sp + 8192 + 512);
        #pragma unroll
        for (int k = 0; k < 16; k += 2) {
            bf16x8 b0_n, b1_n, b0_m, b1_m;
            if (k < 14) {
                b0_n = *(const bf16x8*)(sp + (size_t)(k + 2) * 8192);
                b1_n = *(const bf16x8*)(sp + (size_t)(k + 2) * 8192 + 512);
                b0_m = *(const bf16x8*)(sp + (size_t)(k + 3) * 8192);
                b1_m = *(const bf16x8*)(sp + (size_t)(k + 3) * 8192 + 512);
            }
            int ba0 = row * 512 + ((k * 32 + khalf * 16) ^ ((row & 15) << 4));
            bf16x8 a0 = *(const bf16x8*)((const char*)buf + ba0);
            acc0 = __builtin_amdgcn_mfma_f32_32x32x16_bf16(a0, b0_c, acc0, 0, 0, 0);
            acc1 = __builtin_amdgcn_mfma_f32_32x32x16_bf16(a0, b1_c, acc1, 0, 0, 0);
            int ba1 = row * 512 + (((k + 1) * 32 + khalf * 16) ^ ((row & 15) << 4));
            bf16x8 a1 = *(const bf16x8*)((const char*)buf + ba1);
            acc0 = __builtin_amdgcn_mfma_f32_32x32x16_bf16(a1, b0_d, acc0, 0, 0, 0);
            acc1 = __builtin_amdgcn_mfma_f32_32x32x16_bf16(a1, b1_d, acc1, 0, 0, 0);
            if (k < 14) { b0_c = b0_n; b1_c = b1_n; b0_d = b0_m; b1_d = b1_m; }
        }
    };
    auto epilogue = [&](int tile, const f32x16& acc0, const f32x16& acc1) {
        int tb = rb + tile * BM;
        #pragma unroll
        for (int pass = 0; pass < 2; ++pass) {
            const f32x16& ac = pass ? acc1 : acc0;
            #pragma unroll
            for (int reg = 0; reg < 16; ++reg) {
                int r = (reg & 3) + 8 * (reg >> 2) + 4 * khalf;
                sc[r * 256 + wid * 32 + row] = ac[reg];   // 2-way bank alias: free
            }
            __syncthreads();
            #pragma unroll
            for (int j = 0; j < 4; ++j) {
                int c = tid + j * 512;
                int r = c >> 6, cc = c & 63;
                int gcol = (cc >> 3) * 64 + (cc & 7) * 4 + pass * 32;
                size_t g = (size_t)(tb + r) * 1024 + gcol;
                f32x4 v  = *(const f32x4*)(sc + r * 256 + cc * 4);
                f32x4 pv = __builtin_nontemporal_load((const f32x4*)(pq + g));
                __builtin_nontemporal_store(pv + v, (f32x4*)(out + g));
            }
            __syncthreads();
        }
    };

    f32x16 acc0, acc1;
    // prologue: phase 0 synchronous
    issue_loads(0);
    write_back(0);
    __syncthreads();

    for (int ph = 0; ph < 2 * TILES; ++ph) {
        if ((ph & 1) == 0) { acc0 = f32x16{}; acc1 = f32x16{}; }
        if (ph + 1 < 2 * TILES) issue_loads(ph + 1);     // in flight across k-half
        khalf_loop(ph, acc0, acc1);
        if (ph + 1 < 2 * TILES) write_back(ph + 1);      // passthrough + LDS fill
        __syncthreads();
        if (ph & 1) epilogue(ph >> 1, acc0, acc1);
    }
}

extern "C" void kernel_launch(void* const* d_in, const int* in_sizes, int n_in,
                              void* d_out, int out_size, void* d_ws, size_t ws_size,
                              hipStream_t stream) {
    const float* pq = (const float*)d_in[0];
    const float* A  = (const float*)d_in[1];
    float* out = (float*)d_out;
    unsigned short* Sf = (unsigned short*)d_ws;   // 512 KB fragment-ordered S

    prep_Sfrag<<<512, 64, 0, stream>>>(A, Sf);
    gemm_kernel<<<NBLK, THREADS, 0, stream>>>(pq, Sf, out);
}